// Round 1
// baseline (197.831 us; speedup 1.0000x reference)
//
#include <hip/hip_runtime.h>

// LowImpactLEEA collapses algebraically:
//   softmax(..., axis=2) summed over axis=2  ==  1   (exactly, per (b,n,s))
//   => attn_agg = ones(B,N,S)
//   => leea_out[d] = sum_s Wv[d,s] + bv[d]          (constant over b,n)
//   => out = x + sigmoid(gate) * (rowsum(Wv) + bv)
// So the kernel is a broadcast-add over x. mask/distances/Wk/bk/topk are dead.

#define D_MODEL 256
#define S_DIM   32

__global__ __launch_bounds__(256)
void leea_broadcast_add(const float* __restrict__ x,
                        const float* __restrict__ Wv,
                        const float* __restrict__ bv,
                        const float* __restrict__ gate,
                        float* __restrict__ out,
                        int total_vec4)
{
    __shared__ float c[D_MODEL];
    const int t = threadIdx.x;

    // c[t] = sigmoid(gate) * (sum_s Wv[t, s] + bv[t]); Wv is (D=256, S=32) row-major.
    {
        const float g   = gate[0];
        const float sig = 1.0f / (1.0f + expf(-g));
        const float4* wv4 = reinterpret_cast<const float4*>(Wv + t * S_DIM);
        float s = 0.0f;
#pragma unroll
        for (int j = 0; j < S_DIM / 4; ++j) {
            float4 v = wv4[j];
            s += v.x + v.y + v.z + v.w;
        }
        c[t] = sig * (s + bv[t]);
    }
    __syncthreads();

    const int gid    = blockIdx.x * blockDim.x + t;
    const int stride = gridDim.x * blockDim.x;   // multiple of 64 -> d-slot loop-invariant

    // Each float4 covers d = 4*(vecIdx % 64) .. +3 (D_MODEL/4 == 64).
    const int d4 = (gid & 63) * 4;
    const float4 cv = make_float4(c[d4], c[d4 + 1], c[d4 + 2], c[d4 + 3]);

    const float4* __restrict__ x4 = reinterpret_cast<const float4*>(x);
    float4* __restrict__ o4       = reinterpret_cast<float4*>(out);

    for (int i = gid; i < total_vec4; i += stride) {
        float4 v = x4[i];
        v.x += cv.x; v.y += cv.y; v.z += cv.z; v.w += cv.w;
        o4[i] = v;
    }
}

extern "C" void kernel_launch(void* const* d_in, const int* in_sizes, int n_in,
                              void* d_out, int out_size, void* d_ws, size_t ws_size,
                              hipStream_t stream)
{
    // setup_inputs order: x, mask, distances, Wk, bk, Wv, bv, gate
    const float* x    = (const float*)d_in[0];
    const float* Wv   = (const float*)d_in[5];
    const float* bv   = (const float*)d_in[6];
    const float* gate = (const float*)d_in[7];
    float* out        = (float*)d_out;

    const int total      = in_sizes[0];      // B*N*D = 8*2048*256
    const int total_vec4 = total / 4;        // 1,048,576

    const int threads = 256;
    const int blocks  = 2048;                // ~8 blocks/CU on 256 CUs, grid-stride

    leea_broadcast_add<<<blocks, threads, 0, stream>>>(x, Wv, bv, gate, out, total_vec4);
}